// Round 3
// baseline (876.591 us; speedup 1.0000x reference)
//
#include <hip/hip_runtime.h>
#include <stdint.h>

typedef unsigned short u16;
typedef short v8s __attribute__((ext_vector_type(8)));
typedef float v4f __attribute__((ext_vector_type(4)));

static __device__ __forceinline__ float b2f(u16 u) {
    union { float f; uint32_t i; } v; v.i = ((uint32_t)u) << 16; return v.f;
}
static __device__ __forceinline__ u16 f2b(float f) {
    union { float f; uint32_t i; } v; v.f = f;
    uint32_t x = v.i;
    return (u16)((x + 0x7fffu + ((x >> 16) & 1u)) >> 16);
}

// ---------------- split f32 -> hi/lo bf16, elementwise ----------------
__global__ __launch_bounds__(256) void split_f32(const float* __restrict__ in,
                                                 u16* __restrict__ h, u16* __restrict__ l, int n4) {
    const int i = blockIdx.x * 256 + threadIdx.x;
    if (i >= n4) return;
    const float4 v = ((const float4*)in)[i];
    u16 hh[4], ll[4];
    const float vv[4] = {v.x, v.y, v.z, v.w};
#pragma unroll
    for (int j = 0; j < 4; ++j) {
        hh[j] = f2b(vv[j]);
        ll[j] = f2b(vv[j] - b2f(hh[j]));
    }
    *(uint2*)(h + (size_t)i * 4) = *(const uint2*)hh;
    *(uint2*)(l + (size_t)i * 4) = *(const uint2*)ll;
}

// ---------------- transpose f32 [R][C] -> bf16 [C][R], optional lo part ----------------
template<bool LO>
__global__ __launch_bounds__(256) void transpose_f32(
    const float* __restrict__ in, long ld_in,
    u16* __restrict__ outh, u16* __restrict__ outl, long ld_out)
{
    __shared__ float tile[32][33];
    const int r0 = blockIdx.y * 32, c0 = blockIdx.x * 32;
    for (int i = threadIdx.y; i < 32; i += 8)
        tile[i][threadIdx.x] = in[(long)(r0 + i) * ld_in + c0 + threadIdx.x];
    __syncthreads();
    for (int i = threadIdx.y; i < 32; i += 8) {
        const float v = tile[threadIdx.x][i];
        const u16 hh = f2b(v);
        outh[(long)(c0 + i) * ld_out + r0 + threadIdx.x] = hh;
        if (LO) outl[(long)(c0 + i) * ld_out + r0 + threadIdx.x] = f2b(v - b2f(hh));
    }
}

// ---------------- transpose bf16 [R][C] -> bf16 [C][R], batched ----------------
__global__ __launch_bounds__(256) void transpose_bf16(
    const u16* __restrict__ in, long ld_in, long bsi,
    u16* __restrict__ out, long ld_out, long bso)
{
    __shared__ u16 tile[32][33];
    const long b = blockIdx.z;
    in += b * bsi; out += b * bso;
    const int r0 = blockIdx.y * 32, c0 = blockIdx.x * 32;
    for (int i = threadIdx.y; i < 32; i += 8)
        tile[i][threadIdx.x] = in[(long)(r0 + i) * ld_in + c0 + threadIdx.x];
    __syncthreads();
    for (int i = threadIdx.y; i < 32; i += 8)
        out[(long)(c0 + i) * ld_out + r0 + threadIdx.x] = tile[threadIdx.x][i];
}

// ======== 3-segment GEMM (emulated-f32): C = sum_s A_s @ B_s^T, Kseg=1024 each ========
// OUT_SPLIT: write Ch=bf16(val+bias), Cl=bf16(residual). else: write f32 (no bias).
template<bool OUT_SPLIT>
__global__ __launch_bounds__(256) void gemm3(
    const u16* __restrict__ A0, const u16* __restrict__ A1, const u16* __restrict__ A2, long Asb,
    const u16* __restrict__ B0, const u16* __restrict__ B1, const u16* __restrict__ B2, long Bsb,
    void* __restrict__ C0, void* __restrict__ C1, long ldc, long Csb,
    const float* __restrict__ bias)
{
    alignas(16) __shared__ u16 As[128 * 32];
    alignas(16) __shared__ u16 Bs[128 * 32];
    const int t = threadIdx.x;
    const long b = blockIdx.z;
    const u16* Ag[3] = {A0 + b * Asb, A1 + b * Asb, A2 + b * Asb};
    const u16* Bg[3] = {B0 + b * Bsb, B1 + b * Bsb, B2 + b * Bsb};
    const long m0 = (long)blockIdx.y * 128;
    const long n0 = (long)blockIdx.x * 128;
    const int lane = t & 63, wave = t >> 6;
    const int wm = (wave >> 1) * 64, wn = (wave & 1) * 64;
    const int l16 = lane & 15, quad = lane >> 4;

    v4f acc[4][4];
#pragma unroll
    for (int i = 0; i < 4; ++i)
#pragma unroll
        for (int j = 0; j < 4; ++j)
            acc[i][j] = (v4f){0.f, 0.f, 0.f, 0.f};

    const int e0 = t * 8, r0 = e0 >> 5, c0 = e0 & 31;
    const int e1 = (256 + t) * 8, r1 = e1 >> 5, c1 = e1 & 31;

    for (int s = 0; s < 3; ++s) {
        const u16* A = Ag[s];
        const u16* B = Bg[s];
        for (int k0 = 0; k0 < 1024; k0 += 32) {
            __syncthreads();
            *(uint4*)&As[e0] = *(const uint4*)&A[(m0 + r0) * 1024 + k0 + c0];
            *(uint4*)&As[e1] = *(const uint4*)&A[(m0 + r1) * 1024 + k0 + c1];
            *(uint4*)&Bs[e0] = *(const uint4*)&B[(n0 + r0) * 1024 + k0 + c0];
            *(uint4*)&Bs[e1] = *(const uint4*)&B[(n0 + r1) * 1024 + k0 + c1];
            __syncthreads();

            v8s af[4], bfr[4];
#pragma unroll
            for (int i = 0; i < 4; ++i)
                af[i] = *(const v8s*)&As[(wm + i * 16 + l16) * 32 + quad * 8];
#pragma unroll
            for (int j = 0; j < 4; ++j)
                bfr[j] = *(const v8s*)&Bs[(wn + j * 16 + l16) * 32 + quad * 8];
#pragma unroll
            for (int i = 0; i < 4; ++i)
#pragma unroll
                for (int j = 0; j < 4; ++j)
                    acc[i][j] = __builtin_amdgcn_mfma_f32_16x16x32_bf16(af[i], bfr[j], acc[i][j], 0, 0, 0);
        }
    }

    const long cbase = b * Csb;
#pragma unroll
    for (int j = 0; j < 4; ++j) {
        const long col = n0 + wn + j * 16 + l16;
        const float bv = OUT_SPLIT ? bias[col] : 0.f;
#pragma unroll
        for (int i = 0; i < 4; ++i) {
            const long row = m0 + wm + i * 16 + quad * 4;
#pragma unroll
            for (int r = 0; r < 4; ++r) {
                const float val = acc[i][j][r] + bv;
                const long idx = cbase + (row + r) * ldc + col;
                if (OUT_SPLIT) {
                    const u16 hh = f2b(val);
                    ((u16*)C0)[idx] = hh;
                    ((u16*)C1)[idx] = f2b(val - b2f(hh));
                } else {
                    ((float*)C0)[idx] = val;
                }
            }
        }
    }
}

// ======== plain GEMM: C = A @ B^T (+bias)(+relu), bf16 or f32 out ========
template<bool OUT_F32, bool BIAS, bool RELU>
__global__ __launch_bounds__(256) void gemm_bt(
    const u16* __restrict__ A, long lda, long Asb,
    const u16* __restrict__ B, long ldb, long Bsb,
    void* __restrict__ Cv, long ldc, long Csb,
    const float* __restrict__ bias, int K)
{
    alignas(16) __shared__ u16 As[128 * 32];
    alignas(16) __shared__ u16 Bs[128 * 32];
    const int t = threadIdx.x;
    const long b = blockIdx.z;
    A += b * Asb; B += b * Bsb;
    const long m0 = (long)blockIdx.y * 128;
    const long n0 = (long)blockIdx.x * 128;
    const int lane = t & 63, wave = t >> 6;
    const int wm = (wave >> 1) * 64, wn = (wave & 1) * 64;
    const int l16 = lane & 15, quad = lane >> 4;

    v4f acc[4][4];
#pragma unroll
    for (int i = 0; i < 4; ++i)
#pragma unroll
        for (int j = 0; j < 4; ++j)
            acc[i][j] = (v4f){0.f, 0.f, 0.f, 0.f};

    const int e0 = t * 8, r0 = e0 >> 5, c0 = e0 & 31;
    const int e1 = (256 + t) * 8, r1 = e1 >> 5, c1 = e1 & 31;

    for (int k0 = 0; k0 < K; k0 += 32) {
        __syncthreads();
        *(uint4*)&As[e0] = *(const uint4*)&A[(m0 + r0) * lda + k0 + c0];
        *(uint4*)&As[e1] = *(const uint4*)&A[(m0 + r1) * lda + k0 + c1];
        *(uint4*)&Bs[e0] = *(const uint4*)&B[(n0 + r0) * ldb + k0 + c0];
        *(uint4*)&Bs[e1] = *(const uint4*)&B[(n0 + r1) * ldb + k0 + c1];
        __syncthreads();

        v8s af[4], bfr[4];
#pragma unroll
        for (int i = 0; i < 4; ++i)
            af[i] = *(const v8s*)&As[(wm + i * 16 + l16) * 32 + quad * 8];
#pragma unroll
        for (int j = 0; j < 4; ++j)
            bfr[j] = *(const v8s*)&Bs[(wn + j * 16 + l16) * 32 + quad * 8];
#pragma unroll
        for (int i = 0; i < 4; ++i)
#pragma unroll
            for (int j = 0; j < 4; ++j)
                acc[i][j] = __builtin_amdgcn_mfma_f32_16x16x32_bf16(af[i], bfr[j], acc[i][j], 0, 0, 0);
    }

    const long cbase = b * Csb;
#pragma unroll
    for (int j = 0; j < 4; ++j) {
        const long col = n0 + wn + j * 16 + l16;
        float bv = 0.f;
        if (BIAS) bv = bias[col];
#pragma unroll
        for (int i = 0; i < 4; ++i) {
            const long row = m0 + wm + i * 16 + quad * 4;
#pragma unroll
            for (int r = 0; r < 4; ++r) {
                float val = acc[i][j][r];
                if (BIAS) val += bv;
                if (RELU) val = fmaxf(val, 0.f);
                const long idx = cbase + (row + r) * ldc + col;
                if (OUT_F32) ((float*)Cv)[idx] = val;
                else         ((u16*)Cv)[idx] = f2b(val);
            }
        }
    }
}

// ---------------- softmax over f32 rows of 2048 -> bf16 P in-place at row start ----------------
__global__ __launch_bounds__(256) void softmax_rows(float* __restrict__ S) {
    const long row = blockIdx.x;
    float* p = S + row * 2048;
    const int t = threadIdx.x;
    float v[8];
    float mx = -1e30f;
#pragma unroll
    for (int i = 0; i < 8; ++i) { v[i] = p[t + i * 256]; mx = fmaxf(mx, v[i]); }
    __shared__ float red[256];
    red[t] = mx; __syncthreads();
    for (int off = 128; off > 0; off >>= 1) {
        if (t < off) red[t] = fmaxf(red[t], red[t + off]);
        __syncthreads();
    }
    mx = red[0]; __syncthreads();
    float sum = 0.f;
#pragma unroll
    for (int i = 0; i < 8; ++i) { v[i] = __expf(v[i] - mx); sum += v[i]; }
    red[t] = sum; __syncthreads();
    for (int off = 128; off > 0; off >>= 1) {
        if (t < off) red[t] += red[t + off];
        __syncthreads();
    }
    const float inv = 1.f / red[0];
    u16* q = (u16*)p;
#pragma unroll
    for (int i = 0; i < 8; ++i) q[t + i * 256] = f2b(v[i] * inv);
}

// ---------------- ln1: x = LN(src_f32 + attnO_bf16); writes f32 and bf16 ----------------
__global__ __launch_bounds__(256) void ln_dual(
    const float* __restrict__ a, const u16* __restrict__ bb,
    const float* __restrict__ g, const float* __restrict__ be,
    float* __restrict__ out32, u16* __restrict__ out16)
{
    const long base = (long)blockIdx.x * 1024;
    const int t = threadIdx.x;
    float v[4]; float s = 0.f, ss = 0.f;
#pragma unroll
    for (int i = 0; i < 4; ++i) {
        const int c = t + i * 256;
        const float x = a[base + c] + b2f(bb[base + c]);
        v[i] = x; s += x; ss += x * x;
    }
    __shared__ float rs[256], rss[256];
    rs[t] = s; rss[t] = ss; __syncthreads();
    for (int off = 128; off > 0; off >>= 1) {
        if (t < off) { rs[t] += rs[t + off]; rss[t] += rss[t + off]; }
        __syncthreads();
    }
    const float mean = rs[0] * (1.f / 1024.f);
    const float var = rss[0] * (1.f / 1024.f) - mean * mean;
    const float rstd = rsqrtf(var + 1e-5f);
#pragma unroll
    for (int i = 0; i < 4; ++i) {
        const int c = t + i * 256;
        const float y = (v[i] - mean) * rstd * g[c] + be[c];
        out32[base + c] = y;
        out16[base + c] = f2b(y);
    }
}

// ---------------- ln2: out_f32 = LN(x_f32 + ffO_f32) ----------------
__global__ __launch_bounds__(256) void ln_f32(
    const float* __restrict__ a, const float* __restrict__ bb,
    const float* __restrict__ g, const float* __restrict__ be,
    float* __restrict__ out)
{
    const long base = (long)blockIdx.x * 1024;
    const int t = threadIdx.x;
    float v[4]; float s = 0.f, ss = 0.f;
#pragma unroll
    for (int i = 0; i < 4; ++i) {
        const int c = t + i * 256;
        const float x = a[base + c] + bb[base + c];
        v[i] = x; s += x; ss += x * x;
    }
    __shared__ float rs[256], rss[256];
    rs[t] = s; rss[t] = ss; __syncthreads();
    for (int off = 128; off > 0; off >>= 1) {
        if (t < off) { rs[t] += rs[t + off]; rss[t] += rss[t + off]; }
        __syncthreads();
    }
    const float mean = rs[0] * (1.f / 1024.f);
    const float var = rss[0] * (1.f / 1024.f) - mean * mean;
    const float rstd = rsqrtf(var + 1e-5f);
#pragma unroll
    for (int i = 0; i < 4; ++i) {
        const int c = t + i * 256;
        out[base + c] = (v[i] - mean) * rstd * g[c] + be[c];
    }
}

extern "C" void kernel_launch(void* const* d_in, const int* in_sizes, int n_in,
                              void* d_out, int out_size, void* d_ws, size_t ws_size,
                              hipStream_t stream) {
    (void)in_sizes; (void)n_in; (void)out_size; (void)ws_size;
    constexpr long S = 2048, E = 1024, F = 4096, M = 8192;

    const float* src = (const float*)d_in[0];
    const float* Wq  = (const float*)d_in[1];
    const float* bq  = (const float*)d_in[2];
    const float* Wk  = (const float*)d_in[3];
    const float* bk  = (const float*)d_in[4];
    const float* Wv  = (const float*)d_in[5];
    const float* bv  = (const float*)d_in[6];
    const float* Wo  = (const float*)d_in[7];
    const float* bo  = (const float*)d_in[8];
    const float* W1  = (const float*)d_in[9];
    const float* b1  = (const float*)d_in[10];
    const float* W2  = (const float*)d_in[11];
    const float* b2  = (const float*)d_in[12];
    const float* g1  = (const float*)d_in[13];
    const float* be1 = (const float*)d_in[14];
    const float* g2  = (const float*)d_in[15];
    const float* be2 = (const float*)d_in[16];

    char* ws = (char*)d_ws;
    size_t off = 0;
    auto take = [&](size_t bytes) {
        char* p = ws + off;
        off += (bytes + 255) & ~(size_t)255;
        return p;
    };
    const size_t MB16 = 16777216;  // 8192*1024*2 bytes (bf16 [8192][1024])
    u16* srch  = (u16*)take(MB16);
    u16* srcl  = (u16*)take(MB16);
    u16* WqTh  = (u16*)take(E * E * 2);
    u16* WqTl  = (u16*)take(E * E * 2);
    u16* WkTh  = (u16*)take(E * E * 2);
    u16* WkTl  = (u16*)take(E * E * 2);
    u16* WvT   = (u16*)take(E * E * 2);
    u16* WoT   = (u16*)take(E * E * 2);
    char* R1   = take(4ull * S * S * 4);   // 67.1 MB
    char* R2   = take(5 * MB16);           // 80 MB

    // R1 internal (time-multiplexed)
    u16*   Vb  = (u16*)R1;                       // [0,16M)   until VT transpose
    float* Sf  = (float*)R1;                     // [0,67.1M) scores f32; P bf16 in-place
    u16*   xb  = (u16*)R1;                       // [0,16M)   after PV
    float* ffO = (float*)(R1 + MB16);            // [16M,48M) after attnO dead
    u16*   W1T = (u16*)(R1 + 3 * MB16);          // [48M,56M) transposed after PV
    u16*   W2T = (u16*)(R1 + 3 * MB16 + 8388608);// [56M,64M)
    // R2 internal
    u16* Qh    = (u16*)R2;                       // [0,16M)
    u16* Ql    = (u16*)(R2 + MB16);              // [16M,32M)
    u16* Kh    = (u16*)(R2 + 2 * MB16);          // [32M,48M)
    u16* Kl    = (u16*)(R2 + 3 * MB16);          // [48M,64M)
    u16* VT    = (u16*)(R2 + 4 * MB16);          // [64M,80M)
    u16* attn  = (u16*)R2;                       // [0,16M)   after scores
    u16* attnO = (u16*)(R2 + MB16);              // [16M,32M) after PV
    float* x32 = (float*)srch;                   // 32MB over srch+srcl after PV

    dim3 blk(256), tb(32, 8);

    // 1) split src into hi/lo bf16
    split_f32<<<dim3(M * E / 4 / 256), blk, 0, stream>>>(src, srch, srcl, M * E / 4);

    // 2) weight transposes (f32 -> bf16), Wq/Wk also lo part
    transpose_f32<true ><<<dim3(32, 32), tb, 0, stream>>>(Wq, E, WqTh, WqTl, E);
    transpose_f32<true ><<<dim3(32, 32), tb, 0, stream>>>(Wk, E, WkTh, WkTl, E);
    transpose_f32<false><<<dim3(32, 32), tb, 0, stream>>>(Wv, E, WvT, nullptr, E);
    transpose_f32<false><<<dim3(32, 32), tb, 0, stream>>>(Wo, E, WoT, nullptr, E);

    // 3) Q,K projections (emulated f32), split epilogue -> Qh/Ql, Kh/Kl
    gemm3<true><<<dim3(8, 64, 1), blk, 0, stream>>>(
        srch, srcl, srch, 0, WqTh, WqTh, WqTl, 0, Qh, Ql, E, 0, bq);
    gemm3<true><<<dim3(8, 64, 1), blk, 0, stream>>>(
        srch, srcl, srch, 0, WkTh, WkTh, WkTl, 0, Kh, Kl, E, 0, bk);

    // 4) V projection (plain bf16) then V^T per batch
    gemm_bt<false, true, false><<<dim3(8, 64, 1), blk, 0, stream>>>(
        srch, E, 0, WvT, E, 0, Vb, E, 0, bv, E);
    transpose_bf16<<<dim3(32, 64, 4), tb, 0, stream>>>(
        Vb, E, S * E, VT, S, E * S);

    // 5) scores (emulated f32): Sf[b] = Qh@Kh^T + Ql@Kh^T + Qh@Kl^T
    gemm3<false><<<dim3(16, 16, 4), blk, 0, stream>>>(
        Qh, Ql, Qh, S * E, Kh, Kh, Kl, S * E, Sf, nullptr, S, S * S, nullptr);

    // 6) softmax (f32 in, bf16 P in-place, row pitch 4096 u16)
    softmax_rows<<<dim3(M), blk, 0, stream>>>(Sf);

    // 7) attn[b] = P[b] @ V[b]
    gemm_bt<false, false, false><<<dim3(8, 16, 4), blk, 0, stream>>>(
        (const u16*)Sf, 2 * S, S * 2 * S, VT, S, E * S, attn, E, S * E, nullptr, S);

    // 8) attnO = attn @ Wo + bo (bf16)
    gemm_bt<false, true, false><<<dim3(8, 64, 1), blk, 0, stream>>>(
        attn, E, 0, WoT, E, 0, attnO, E, 0, bo, E);

    // 9) x = LN(src + attnO) -> x32 (f32) and xb (bf16)
    ln_dual<<<dim3(M), blk, 0, stream>>>(src, attnO, g1, be1, x32, xb);

    // 10) FFN weight transposes (into dead score region)
    transpose_f32<false><<<dim3(128, 32), tb, 0, stream>>>(W1, F, W1T, nullptr, E);  // [1024][4096]->[4096][1024]
    transpose_f32<false><<<dim3(32, 128), tb, 0, stream>>>(W2, E, W2T, nullptr, F);  // [4096][1024]->[1024][4096]

    // 11) h = relu(xb @ W1 + b1) (bf16) into R2 (all dead)
    u16* h = (u16*)R2;
    gemm_bt<false, true, true><<<dim3(32, 64, 1), blk, 0, stream>>>(
        xb, E, 0, W1T, E, 0, h, F, 0, b1, E);

    // 12) ffO = h @ W2 + b2 (f32)
    gemm_bt<true, true, false><<<dim3(8, 64, 1), blk, 0, stream>>>(
        h, F, 0, W2T, F, 0, ffO, E, 0, b2, F);

    // 13) out = LN(x32 + ffO) -> f32
    ln_f32<<<dim3(M), blk, 0, stream>>>(x32, ffO, g2, be2, (float*)d_out);
}

// Round 4
// 848.908 us; speedup vs baseline: 1.0326x; 1.0326x over previous
//
#include <hip/hip_runtime.h>
#include <stdint.h>

typedef unsigned short u16;
typedef short v8s __attribute__((ext_vector_type(8)));
typedef float v4f __attribute__((ext_vector_type(4)));

static __device__ __forceinline__ float b2f(u16 u) {
    union { float f; uint32_t i; } v; v.i = ((uint32_t)u) << 16; return v.f;
}
static __device__ __forceinline__ u16 f2b(float f) {
    union { float f; uint32_t i; } v; v.f = f;
    uint32_t x = v.i;
    return (u16)((x + 0x7fffu + ((x >> 16) & 1u)) >> 16);
}

// async global->LDS, 16B per lane. lds dest = wave-uniform base + lane*16.
static __device__ __forceinline__ void gload_lds16(const u16* g, const u16* l) {
    __builtin_amdgcn_global_load_lds(
        (const __attribute__((address_space(1))) uint32_t*)(uintptr_t)g,
        (__attribute__((address_space(3))) uint32_t*)(uintptr_t)l,
        16, 0, 0);
}

// ---------------- split f32 -> hi/lo bf16, elementwise ----------------
__global__ __launch_bounds__(256) void split_f32(const float* __restrict__ in,
                                                 u16* __restrict__ h, u16* __restrict__ l, int n4) {
    const int i = blockIdx.x * 256 + threadIdx.x;
    if (i >= n4) return;
    const float4 v = ((const float4*)in)[i];
    u16 hh[4], ll[4];
    const float vv[4] = {v.x, v.y, v.z, v.w};
#pragma unroll
    for (int j = 0; j < 4; ++j) {
        hh[j] = f2b(vv[j]);
        ll[j] = f2b(vv[j] - b2f(hh[j]));
    }
    *(uint2*)(h + (size_t)i * 4) = *(const uint2*)hh;
    *(uint2*)(l + (size_t)i * 4) = *(const uint2*)ll;
}

// ---------------- transpose f32 [R][C] -> bf16 [C][R], optional lo part ----------------
template<bool LO>
__global__ __launch_bounds__(256) void transpose_f32(
    const float* __restrict__ in, long ld_in,
    u16* __restrict__ outh, u16* __restrict__ outl, long ld_out)
{
    __shared__ float tile[32][33];
    const int r0 = blockIdx.y * 32, c0 = blockIdx.x * 32;
    for (int i = threadIdx.y; i < 32; i += 8)
        tile[i][threadIdx.x] = in[(long)(r0 + i) * ld_in + c0 + threadIdx.x];
    __syncthreads();
    for (int i = threadIdx.y; i < 32; i += 8) {
        const float v = tile[threadIdx.x][i];
        const u16 hh = f2b(v);
        outh[(long)(c0 + i) * ld_out + r0 + threadIdx.x] = hh;
        if (LO) outl[(long)(c0 + i) * ld_out + r0 + threadIdx.x] = f2b(v - b2f(hh));
    }
}

// ---------------- transpose bf16 [R][C] -> bf16 [C][R], batched ----------------
__global__ __launch_bounds__(256) void transpose_bf16(
    const u16* __restrict__ in, long ld_in, long bsi,
    u16* __restrict__ out, long ld_out, long bso)
{
    __shared__ u16 tile[32][33];
    const long b = blockIdx.z;
    in += b * bsi; out += b * bso;
    const int r0 = blockIdx.y * 32, c0 = blockIdx.x * 32;
    for (int i = threadIdx.y; i < 32; i += 8)
        tile[i][threadIdx.x] = in[(long)(r0 + i) * ld_in + c0 + threadIdx.x];
    __syncthreads();
    for (int i = threadIdx.y; i < 32; i += 8)
        out[(long)(c0 + i) * ld_out + r0 + threadIdx.x] = tile[threadIdx.x][i];
}

// ======== 3-segment GEMM (emulated-f32): C = sum_s A_s @ B_s^T, Kseg=1024 each ========
template<bool OUT_SPLIT>
__global__ __launch_bounds__(256) void gemm3(
    const u16* __restrict__ A0, const u16* __restrict__ A1, const u16* __restrict__ A2, long Asb,
    const u16* __restrict__ B0, const u16* __restrict__ B1, const u16* __restrict__ B2, long Bsb,
    void* __restrict__ C0, void* __restrict__ C1, long ldc, long Csb,
    const float* __restrict__ bias)
{
    alignas(16) __shared__ u16 As[128 * 32];
    alignas(16) __shared__ u16 Bs[128 * 32];
    const int t = threadIdx.x;
    const long b = blockIdx.z;
    const u16* Ag[3] = {A0 + b * Asb, A1 + b * Asb, A2 + b * Asb};
    const u16* Bg[3] = {B0 + b * Bsb, B1 + b * Bsb, B2 + b * Bsb};
    const long m0 = (long)blockIdx.y * 128;
    const long n0 = (long)blockIdx.x * 128;
    const int lane = t & 63, wave = t >> 6;
    const int wm = (wave >> 1) * 64, wn = (wave & 1) * 64;
    const int l16 = lane & 15, quad = lane >> 4;

    v4f acc[4][4];
#pragma unroll
    for (int i = 0; i < 4; ++i)
#pragma unroll
        for (int j = 0; j < 4; ++j)
            acc[i][j] = (v4f){0.f, 0.f, 0.f, 0.f};

    // staging geometry: thread t handles elements t*8 (pass0) and (256+t)*8 (pass1)
    const int r0 = t >> 2, c0 = (t & 3) * 8;      // pass0: row t/4, col (t%4)*8
    const int r1 = 64 + r0, c1 = c0;              // pass1
    const u16* lA0 = As + wave * 512;             // wave-uniform LDS bases (elements)
    const u16* lA1 = As + 2048 + wave * 512;
    const u16* lB0 = Bs + wave * 512;
    const u16* lB1 = Bs + 2048 + wave * 512;

    for (int s = 0; s < 3; ++s) {
        const u16* A = Ag[s];
        const u16* B = Bg[s];
        for (int k0 = 0; k0 < 1024; k0 += 32) {
            __syncthreads();
            gload_lds16(&A[(m0 + r0) * 1024 + k0 + c0], lA0);
            gload_lds16(&A[(m0 + r1) * 1024 + k0 + c1], lA1);
            gload_lds16(&B[(n0 + r0) * 1024 + k0 + c0], lB0);
            gload_lds16(&B[(n0 + r1) * 1024 + k0 + c1], lB1);
            __syncthreads();

            v8s af[4], bfr[4];
#pragma unroll
            for (int i = 0; i < 4; ++i)
                af[i] = *(const v8s*)&As[(wm + i * 16 + l16) * 32 + quad * 8];
#pragma unroll
            for (int j = 0; j < 4; ++j)
                bfr[j] = *(const v8s*)&Bs[(wn + j * 16 + l16) * 32 + quad * 8];
#pragma unroll
            for (int i = 0; i < 4; ++i)
#pragma unroll
                for (int j = 0; j < 4; ++j)
                    acc[i][j] = __builtin_amdgcn_mfma_f32_16x16x32_bf16(af[i], bfr[j], acc[i][j], 0, 0, 0);
        }
    }

    const long cbase = b * Csb;
#pragma unroll
    for (int j = 0; j < 4; ++j) {
        const long col = n0 + wn + j * 16 + l16;
        const float bv = OUT_SPLIT ? bias[col] : 0.f;
#pragma unroll
        for (int i = 0; i < 4; ++i) {
            const long row = m0 + wm + i * 16 + quad * 4;
#pragma unroll
            for (int r = 0; r < 4; ++r) {
                const float val = acc[i][j][r] + bv;
                const long idx = cbase + (row + r) * ldc + col;
                if (OUT_SPLIT) {
                    const u16 hh = f2b(val);
                    ((u16*)C0)[idx] = hh;
                    ((u16*)C1)[idx] = f2b(val - b2f(hh));
                } else {
                    ((float*)C0)[idx] = val;
                }
            }
        }
    }
}

// ======== plain GEMM: C = A @ B^T (+bias)(+relu), bf16 or f32 out ========
template<bool OUT_F32, bool BIAS, bool RELU>
__global__ __launch_bounds__(256) void gemm_bt(
    const u16* __restrict__ A, long lda, long Asb,
    const u16* __restrict__ B, long ldb, long Bsb,
    void* __restrict__ Cv, long ldc, long Csb,
    const float* __restrict__ bias, int K)
{
    alignas(16) __shared__ u16 As[128 * 32];
    alignas(16) __shared__ u16 Bs[128 * 32];
    const int t = threadIdx.x;
    const long b = blockIdx.z;
    A += b * Asb; B += b * Bsb;
    const long m0 = (long)blockIdx.y * 128;
    const long n0 = (long)blockIdx.x * 128;
    const int lane = t & 63, wave = t >> 6;
    const int wm = (wave >> 1) * 64, wn = (wave & 1) * 64;
    const int l16 = lane & 15, quad = lane >> 4;

    v4f acc[4][4];
#pragma unroll
    for (int i = 0; i < 4; ++i)
#pragma unroll
        for (int j = 0; j < 4; ++j)
            acc[i][j] = (v4f){0.f, 0.f, 0.f, 0.f};

    const int r0 = t >> 2, c0 = (t & 3) * 8;
    const int r1 = 64 + r0, c1 = c0;
    const u16* lA0 = As + wave * 512;
    const u16* lA1 = As + 2048 + wave * 512;
    const u16* lB0 = Bs + wave * 512;
    const u16* lB1 = Bs + 2048 + wave * 512;

    for (int k0 = 0; k0 < K; k0 += 32) {
        __syncthreads();
        gload_lds16(&A[(m0 + r0) * lda + k0 + c0], lA0);
        gload_lds16(&A[(m0 + r1) * lda + k0 + c1], lA1);
        gload_lds16(&B[(n0 + r0) * ldb + k0 + c0], lB0);
        gload_lds16(&B[(n0 + r1) * ldb + k0 + c1], lB1);
        __syncthreads();

        v8s af[4], bfr[4];
#pragma unroll
        for (int i = 0; i < 4; ++i)
            af[i] = *(const v8s*)&As[(wm + i * 16 + l16) * 32 + quad * 8];
#pragma unroll
        for (int j = 0; j < 4; ++j)
            bfr[j] = *(const v8s*)&Bs[(wn + j * 16 + l16) * 32 + quad * 8];
#pragma unroll
        for (int i = 0; i < 4; ++i)
#pragma unroll
            for (int j = 0; j < 4; ++j)
                acc[i][j] = __builtin_amdgcn_mfma_f32_16x16x32_bf16(af[i], bfr[j], acc[i][j], 0, 0, 0);
    }

    const long cbase = b * Csb;
#pragma unroll
    for (int j = 0; j < 4; ++j) {
        const long col = n0 + wn + j * 16 + l16;
        float bv = 0.f;
        if (BIAS) bv = bias[col];
#pragma unroll
        for (int i = 0; i < 4; ++i) {
            const long row = m0 + wm + i * 16 + quad * 4;
#pragma unroll
            for (int r = 0; r < 4; ++r) {
                float val = acc[i][j][r];
                if (BIAS) val += bv;
                if (RELU) val = fmaxf(val, 0.f);
                const long idx = cbase + (row + r) * ldc + col;
                if (OUT_F32) ((float*)Cv)[idx] = val;
                else         ((u16*)Cv)[idx] = f2b(val);
            }
        }
    }
}

// ---------------- softmax over f32 rows of 2048 -> bf16 P in-place at row start ----------------
__global__ __launch_bounds__(256) void softmax_rows(float* __restrict__ S) {
    const long row = blockIdx.x;
    float* p = S + row * 2048;
    const int t = threadIdx.x;
    float v[8];
    float mx = -1e30f;
#pragma unroll
    for (int i = 0; i < 8; ++i) { v[i] = p[t + i * 256]; mx = fmaxf(mx, v[i]); }
    __shared__ float red[256];
    red[t] = mx; __syncthreads();
    for (int off = 128; off > 0; off >>= 1) {
        if (t < off) red[t] = fmaxf(red[t], red[t + off]);
        __syncthreads();
    }
    mx = red[0]; __syncthreads();
    float sum = 0.f;
#pragma unroll
    for (int i = 0; i < 8; ++i) { v[i] = __expf(v[i] - mx); sum += v[i]; }
    red[t] = sum; __syncthreads();
    for (int off = 128; off > 0; off >>= 1) {
        if (t < off) red[t] += red[t + off];
        __syncthreads();
    }
    const float inv = 1.f / red[0];
    u16* q = (u16*)p;
#pragma unroll
    for (int i = 0; i < 8; ++i) q[t + i * 256] = f2b(v[i] * inv);
}

// ---------------- ln1: x = LN(src_f32 + attnO_bf16); writes f32 and bf16 ----------------
__global__ __launch_bounds__(256) void ln_dual(
    const float* __restrict__ a, const u16* __restrict__ bb,
    const float* __restrict__ g, const float* __restrict__ be,
    float* __restrict__ out32, u16* __restrict__ out16)
{
    const long base = (long)blockIdx.x * 1024;
    const int t = threadIdx.x;
    float v[4]; float s = 0.f, ss = 0.f;
#pragma unroll
    for (int i = 0; i < 4; ++i) {
        const int c = t + i * 256;
        const float x = a[base + c] + b2f(bb[base + c]);
        v[i] = x; s += x; ss += x * x;
    }
    __shared__ float rs[256], rss[256];
    rs[t] = s; rss[t] = ss; __syncthreads();
    for (int off = 128; off > 0; off >>= 1) {
        if (t < off) { rs[t] += rs[t + off]; rss[t] += rss[t + off]; }
        __syncthreads();
    }
    const float mean = rs[0] * (1.f / 1024.f);
    const float var = rss[0] * (1.f / 1024.f) - mean * mean;
    const float rstd = rsqrtf(var + 1e-5f);
#pragma unroll
    for (int i = 0; i < 4; ++i) {
        const int c = t + i * 256;
        const float y = (v[i] - mean) * rstd * g[c] + be[c];
        out32[base + c] = y;
        out16[base + c] = f2b(y);
    }
}

// ---------------- ln2: out_f32 = LN(x_f32 + ffO_f32) ----------------
__global__ __launch_bounds__(256) void ln_f32(
    const float* __restrict__ a, const float* __restrict__ bb,
    const float* __restrict__ g, const float* __restrict__ be,
    float* __restrict__ out)
{
    const long base = (long)blockIdx.x * 1024;
    const int t = threadIdx.x;
    float v[4]; float s = 0.f, ss = 0.f;
#pragma unroll
    for (int i = 0; i < 4; ++i) {
        const int c = t + i * 256;
        const float x = a[base + c] + bb[base + c];
        v[i] = x; s += x; ss += x * x;
    }
    __shared__ float rs[256], rss[256];
    rs[t] = s; rss[t] = ss; __syncthreads();
    for (int off = 128; off > 0; off >>= 1) {
        if (t < off) { rs[t] += rs[t + off]; rss[t] += rss[t + off]; }
        __syncthreads();
    }
    const float mean = rs[0] * (1.f / 1024.f);
    const float var = rss[0] * (1.f / 1024.f) - mean * mean;
    const float rstd = rsqrtf(var + 1e-5f);
#pragma unroll
    for (int i = 0; i < 4; ++i) {
        const int c = t + i * 256;
        out[base + c] = (v[i] - mean) * rstd * g[c] + be[c];
    }
}

extern "C" void kernel_launch(void* const* d_in, const int* in_sizes, int n_in,
                              void* d_out, int out_size, void* d_ws, size_t ws_size,
                              hipStream_t stream) {
    (void)in_sizes; (void)n_in; (void)out_size; (void)ws_size;
    constexpr long S = 2048, E = 1024, F = 4096, M = 8192;

    const float* src = (const float*)d_in[0];
    const float* Wq  = (const float*)d_in[1];
    const float* bq  = (const float*)d_in[2];
    const float* Wk  = (const float*)d_in[3];
    const float* bk  = (const float*)d_in[4];
    const float* Wv  = (const float*)d_in[5];
    const float* bv  = (const float*)d_in[6];
    const float* Wo  = (const float*)d_in[7];
    const float* bo  = (const float*)d_in[8];
    const float* W1  = (const float*)d_in[9];
    const float* b1  = (const float*)d_in[10];
    const float* W2  = (const float*)d_in[11];
    const float* b2  = (const float*)d_in[12];
    const float* g1  = (const float*)d_in[13];
    const float* be1 = (const float*)d_in[14];
    const float* g2  = (const float*)d_in[15];
    const float* be2 = (const float*)d_in[16];

    char* ws = (char*)d_ws;
    size_t off = 0;
    auto take = [&](size_t bytes) {
        char* p = ws + off;
        off += (bytes + 255) & ~(size_t)255;
        return p;
    };
    const size_t MB16 = 16777216;  // bf16 [8192][1024]
    u16* srch  = (u16*)take(MB16);
    u16* srcl  = (u16*)take(MB16);
    u16* WqTh  = (u16*)take(E * E * 2);
    u16* WqTl  = (u16*)take(E * E * 2);
    u16* WkTh  = (u16*)take(E * E * 2);
    u16* WkTl  = (u16*)take(E * E * 2);
    u16* WvT   = (u16*)take(E * E * 2);
    u16* WoT   = (u16*)take(E * E * 2);
    char* R1   = take(4ull * S * S * 4);   // 67.1 MB
    char* R2   = take(5 * MB16);           // 80 MB

    // R1 internal (time-multiplexed)
    u16*   Vb  = (u16*)R1;
    float* Sf  = (float*)R1;
    u16*   xb  = (u16*)R1;
    float* ffO = (float*)(R1 + MB16);
    u16*   W1T = (u16*)(R1 + 3 * MB16);
    u16*   W2T = (u16*)(R1 + 3 * MB16 + 8388608);
    // R2 internal
    u16* Qh    = (u16*)R2;
    u16* Ql    = (u16*)(R2 + MB16);
    u16* Kh    = (u16*)(R2 + 2 * MB16);
    u16* Kl    = (u16*)(R2 + 3 * MB16);
    u16* VT    = (u16*)(R2 + 4 * MB16);
    u16* attn  = (u16*)R2;
    u16* attnO = (u16*)(R2 + MB16);
    float* x32 = (float*)srch;

    dim3 blk(256), tb(32, 8);

    split_f32<<<dim3(M * E / 4 / 256), blk, 0, stream>>>(src, srch, srcl, M * E / 4);

    transpose_f32<true ><<<dim3(32, 32), tb, 0, stream>>>(Wq, E, WqTh, WqTl, E);
    transpose_f32<true ><<<dim3(32, 32), tb, 0, stream>>>(Wk, E, WkTh, WkTl, E);
    transpose_f32<false><<<dim3(32, 32), tb, 0, stream>>>(Wv, E, WvT, nullptr, E);
    transpose_f32<false><<<dim3(32, 32), tb, 0, stream>>>(Wo, E, WoT, nullptr, E);

    gemm3<true><<<dim3(8, 64, 1), blk, 0, stream>>>(
        srch, srcl, srch, 0, WqTh, WqTh, WqTl, 0, Qh, Ql, E, 0, bq);
    gemm3<true><<<dim3(8, 64, 1), blk, 0, stream>>>(
        srch, srcl, srch, 0, WkTh, WkTh, WkTl, 0, Kh, Kl, E, 0, bk);

    gemm_bt<false, true, false><<<dim3(8, 64, 1), blk, 0, stream>>>(
        srch, E, 0, WvT, E, 0, Vb, E, 0, bv, E);
    transpose_bf16<<<dim3(32, 64, 4), tb, 0, stream>>>(
        Vb, E, S * E, VT, S, E * S);

    gemm3<false><<<dim3(16, 16, 4), blk, 0, stream>>>(
        Qh, Ql, Qh, S * E, Kh, Kh, Kl, S * E, Sf, nullptr, S, S * S, nullptr);

    softmax_rows<<<dim3(M), blk, 0, stream>>>(Sf);

    gemm_bt<false, false, false><<<dim3(8, 16, 4), blk, 0, stream>>>(
        (const u16*)Sf, 2 * S, S * 2 * S, VT, S, E * S, attn, E, S * E, nullptr, S);

    gemm_bt<false, true, false><<<dim3(8, 64, 1), blk, 0, stream>>>(
        attn, E, 0, WoT, E, 0, attnO, E, 0, bo, E);

    ln_dual<<<dim3(M), blk, 0, stream>>>(src, attnO, g1, be1, x32, xb);

    transpose_f32<false><<<dim3(128, 32), tb, 0, stream>>>(W1, F, W1T, nullptr, E);
    transpose_f32<false><<<dim3(32, 128), tb, 0, stream>>>(W2, E, W2T, nullptr, F);

    u16* h = (u16*)R2;
    gemm_bt<false, true, true><<<dim3(32, 64, 1), blk, 0, stream>>>(
        xb, E, 0, W1T, E, 0, h, F, 0, b1, E);

    gemm_bt<true, true, false><<<dim3(8, 64, 1), blk, 0, stream>>>(
        h, F, 0, W2T, F, 0, ffO, E, 0, b2, F);

    ln_f32<<<dim3(M), blk, 0, stream>>>(x32, ffO, g2, be2, (float*)d_out);
}

// Round 5
// 732.252 us; speedup vs baseline: 1.1971x; 1.1593x over previous
//
#include <hip/hip_runtime.h>
#include <stdint.h>

typedef unsigned short u16;
typedef short v8s __attribute__((ext_vector_type(8)));
typedef float v4f __attribute__((ext_vector_type(4)));

static __device__ __forceinline__ float b2f(u16 u) {
    union { float f; uint32_t i; } v; v.i = ((uint32_t)u) << 16; return v.f;
}
static __device__ __forceinline__ u16 f2b(float f) {
    union { float f; uint32_t i; } v; v.f = f;
    uint32_t x = v.i;
    return (u16)((x + 0x7fffu + ((x >> 16) & 1u)) >> 16);
}

// async global->LDS, 16B per lane. lds dest = wave-uniform base + lane*16.
static __device__ __forceinline__ void gload_lds16(const u16* g, const u16* l) {
    __builtin_amdgcn_global_load_lds(
        (const __attribute__((address_space(1))) uint32_t*)(uintptr_t)g,
        (__attribute__((address_space(3))) uint32_t*)(uintptr_t)l,
        16, 0, 0);
}

// ---------------- split f32 -> hi/lo bf16, elementwise ----------------
__global__ __launch_bounds__(256) void split_f32(const float* __restrict__ in,
                                                 u16* __restrict__ h, u16* __restrict__ l, int n4) {
    const int i = blockIdx.x * 256 + threadIdx.x;
    if (i >= n4) return;
    const float4 v = ((const float4*)in)[i];
    u16 hh[4], ll[4];
    const float vv[4] = {v.x, v.y, v.z, v.w};
#pragma unroll
    for (int j = 0; j < 4; ++j) {
        hh[j] = f2b(vv[j]);
        ll[j] = f2b(vv[j] - b2f(hh[j]));
    }
    *(uint2*)(h + (size_t)i * 4) = *(const uint2*)hh;
    *(uint2*)(l + (size_t)i * 4) = *(const uint2*)ll;
}

// ---------------- transpose f32 [R][C] -> bf16 [C][R], optional lo part ----------------
template<bool LO>
__global__ __launch_bounds__(256) void transpose_f32(
    const float* __restrict__ in, long ld_in,
    u16* __restrict__ outh, u16* __restrict__ outl, long ld_out)
{
    __shared__ float tile[32][33];
    const int r0 = blockIdx.y * 32, c0 = blockIdx.x * 32;
    for (int i = threadIdx.y; i < 32; i += 8)
        tile[i][threadIdx.x] = in[(long)(r0 + i) * ld_in + c0 + threadIdx.x];
    __syncthreads();
    for (int i = threadIdx.y; i < 32; i += 8) {
        const float v = tile[threadIdx.x][i];
        const u16 hh = f2b(v);
        outh[(long)(c0 + i) * ld_out + r0 + threadIdx.x] = hh;
        if (LO) outl[(long)(c0 + i) * ld_out + r0 + threadIdx.x] = f2b(v - b2f(hh));
    }
}

// ---------------- transpose bf16 [R][C] -> bf16 [C][R], batched ----------------
__global__ __launch_bounds__(256) void transpose_bf16(
    const u16* __restrict__ in, long ld_in, long bsi,
    u16* __restrict__ out, long ld_out, long bso)
{
    __shared__ u16 tile[32][33];
    const long b = blockIdx.z;
    in += b * bsi; out += b * bso;
    const int r0 = blockIdx.y * 32, c0 = blockIdx.x * 32;
    for (int i = threadIdx.y; i < 32; i += 8)
        tile[i][threadIdx.x] = in[(long)(r0 + i) * ld_in + c0 + threadIdx.x];
    __syncthreads();
    for (int i = threadIdx.y; i < 32; i += 8)
        out[(long)(c0 + i) * ld_out + r0 + threadIdx.x] = tile[threadIdx.x][i];
}

// ======== 3-segment GEMM (emulated-f32): C = sum_s A_s @ B_s^T, Kseg=1024 each ========
// BK=64, XOR-swizzled LDS (conflict-free), 32 MFMA per barrier-pair.
template<bool OUT_SPLIT>
__global__ __launch_bounds__(256) void gemm3(
    const u16* __restrict__ A0, const u16* __restrict__ A1, const u16* __restrict__ A2,
    long lda, long Asb,
    const u16* __restrict__ B0, const u16* __restrict__ B1, const u16* __restrict__ B2,
    long ldb, long Bsb,
    void* __restrict__ C0, void* __restrict__ C1, long ldc, long Csb,
    const float* __restrict__ bias)
{
    alignas(16) __shared__ u16 As[128 * 64];
    alignas(16) __shared__ u16 Bs[128 * 64];
    const int t = threadIdx.x;
    const long b = blockIdx.z;
    const u16* Ag[3] = {A0 + b * Asb, A1 + b * Asb, A2 + b * Asb};
    const u16* Bg[3] = {B0 + b * Bsb, B1 + b * Bsb, B2 + b * Bsb};
    const long m0 = (long)blockIdx.y * 128;
    const long n0 = (long)blockIdx.x * 128;
    const int lane = t & 63, wave = t >> 6;
    const int wm = (wave >> 1) * 64, wn = (wave & 1) * 64;
    const int l16 = lane & 15, quad = lane >> 4;

    // staging geometry: per 32-row pass, thread t covers row t>>3, swizzled chunk
    const int rr = t >> 3;                                   // 0..31
    const int cg8 = ((t & 7) ^ ((t >> 3) & 7)) * 8;          // lane-permuted col (elts)
    const int wv512 = wave * 512;                            // wave LDS base in pass

    v4f acc[4][4];
#pragma unroll
    for (int i = 0; i < 4; ++i)
#pragma unroll
        for (int j = 0; j < 4; ++j)
            acc[i][j] = (v4f){0.f, 0.f, 0.f, 0.f};

    for (int s = 0; s < 3; ++s) {
        const u16* A = Ag[s];
        const u16* B = Bg[s];
        for (int k0 = 0; k0 < 1024; k0 += 64) {
            __syncthreads();
#pragma unroll
            for (int p = 0; p < 4; ++p) {
                gload_lds16(&A[(m0 + p * 32 + rr) * lda + k0 + cg8], As + p * 2048 + wv512);
                gload_lds16(&B[(n0 + p * 32 + rr) * ldb + k0 + cg8], Bs + p * 2048 + wv512);
            }
            __syncthreads();

#pragma unroll
            for (int kk = 0; kk < 2; ++kk) {
                const int swz = ((kk * 4 + quad) ^ (l16 & 7)) * 8;
                v8s af[4], bfr[4];
#pragma unroll
                for (int i = 0; i < 4; ++i)
                    af[i] = *(const v8s*)&As[(wm + i * 16 + l16) * 64 + swz];
#pragma unroll
                for (int j = 0; j < 4; ++j)
                    bfr[j] = *(const v8s*)&Bs[(wn + j * 16 + l16) * 64 + swz];
#pragma unroll
                for (int i = 0; i < 4; ++i)
#pragma unroll
                    for (int j = 0; j < 4; ++j)
                        acc[i][j] = __builtin_amdgcn_mfma_f32_16x16x32_bf16(af[i], bfr[j], acc[i][j], 0, 0, 0);
            }
        }
    }

    const long cbase = b * Csb;
#pragma unroll
    for (int j = 0; j < 4; ++j) {
        const long col = n0 + wn + j * 16 + l16;
        const float bv = OUT_SPLIT ? bias[col] : 0.f;
#pragma unroll
        for (int i = 0; i < 4; ++i) {
            const long row = m0 + wm + i * 16 + quad * 4;
#pragma unroll
            for (int r = 0; r < 4; ++r) {
                const float val = acc[i][j][r] + bv;
                const long idx = cbase + (row + r) * ldc + col;
                if (OUT_SPLIT) {
                    const u16 hh = f2b(val);
                    ((u16*)C0)[idx] = hh;
                    ((u16*)C1)[idx] = f2b(val - b2f(hh));
                } else {
                    ((float*)C0)[idx] = val;
                }
            }
        }
    }
}

// ======== plain GEMM: C = A @ B^T (+bias)(+relu), bf16 or f32 out. BK=64 swizzled ========
template<bool OUT_F32, bool BIAS, bool RELU>
__global__ __launch_bounds__(256) void gemm_bt(
    const u16* __restrict__ A, long lda, long Asb,
    const u16* __restrict__ B, long ldb, long Bsb,
    void* __restrict__ Cv, long ldc, long Csb,
    const float* __restrict__ bias, int K)
{
    alignas(16) __shared__ u16 As[128 * 64];
    alignas(16) __shared__ u16 Bs[128 * 64];
    const int t = threadIdx.x;
    const long b = blockIdx.z;
    A += b * Asb; B += b * Bsb;
    const long m0 = (long)blockIdx.y * 128;
    const long n0 = (long)blockIdx.x * 128;
    const int lane = t & 63, wave = t >> 6;
    const int wm = (wave >> 1) * 64, wn = (wave & 1) * 64;
    const int l16 = lane & 15, quad = lane >> 4;

    const int rr = t >> 3;
    const int cg8 = ((t & 7) ^ ((t >> 3) & 7)) * 8;
    const int wv512 = wave * 512;

    v4f acc[4][4];
#pragma unroll
    for (int i = 0; i < 4; ++i)
#pragma unroll
        for (int j = 0; j < 4; ++j)
            acc[i][j] = (v4f){0.f, 0.f, 0.f, 0.f};

    for (int k0 = 0; k0 < K; k0 += 64) {
        __syncthreads();
#pragma unroll
        for (int p = 0; p < 4; ++p) {
            gload_lds16(&A[(m0 + p * 32 + rr) * lda + k0 + cg8], As + p * 2048 + wv512);
            gload_lds16(&B[(n0 + p * 32 + rr) * ldb + k0 + cg8], Bs + p * 2048 + wv512);
        }
        __syncthreads();

#pragma unroll
        for (int kk = 0; kk < 2; ++kk) {
            const int swz = ((kk * 4 + quad) ^ (l16 & 7)) * 8;
            v8s af[4], bfr[4];
#pragma unroll
            for (int i = 0; i < 4; ++i)
                af[i] = *(const v8s*)&As[(wm + i * 16 + l16) * 64 + swz];
#pragma unroll
            for (int j = 0; j < 4; ++j)
                bfr[j] = *(const v8s*)&Bs[(wn + j * 16 + l16) * 64 + swz];
#pragma unroll
            for (int i = 0; i < 4; ++i)
#pragma unroll
                for (int j = 0; j < 4; ++j)
                    acc[i][j] = __builtin_amdgcn_mfma_f32_16x16x32_bf16(af[i], bfr[j], acc[i][j], 0, 0, 0);
        }
    }

    const long cbase = b * Csb;
#pragma unroll
    for (int j = 0; j < 4; ++j) {
        const long col = n0 + wn + j * 16 + l16;
        float bv = 0.f;
        if (BIAS) bv = bias[col];
#pragma unroll
        for (int i = 0; i < 4; ++i) {
            const long row = m0 + wm + i * 16 + quad * 4;
#pragma unroll
            for (int r = 0; r < 4; ++r) {
                float val = acc[i][j][r];
                if (BIAS) val += bv;
                if (RELU) val = fmaxf(val, 0.f);
                const long idx = cbase + (row + r) * ldc + col;
                if (OUT_F32) ((float*)Cv)[idx] = val;
                else         ((u16*)Cv)[idx] = f2b(val);
            }
        }
    }
}

// ---------------- softmax over f32 rows of 2048 -> bf16 P in-place at row start ----------------
__global__ __launch_bounds__(256) void softmax_rows(float* __restrict__ S) {
    const long row = blockIdx.x;
    float* p = S + row * 2048;
    const int t = threadIdx.x;
    float v[8];
    float mx = -1e30f;
#pragma unroll
    for (int i = 0; i < 8; ++i) { v[i] = p[t + i * 256]; mx = fmaxf(mx, v[i]); }
    __shared__ float red[256];
    red[t] = mx; __syncthreads();
    for (int off = 128; off > 0; off >>= 1) {
        if (t < off) red[t] = fmaxf(red[t], red[t + off]);
        __syncthreads();
    }
    mx = red[0]; __syncthreads();
    float sum = 0.f;
#pragma unroll
    for (int i = 0; i < 8; ++i) { v[i] = __expf(v[i] - mx); sum += v[i]; }
    red[t] = sum; __syncthreads();
    for (int off = 128; off > 0; off >>= 1) {
        if (t < off) red[t] += red[t + off];
        __syncthreads();
    }
    const float inv = 1.f / red[0];
    u16* q = (u16*)p;
#pragma unroll
    for (int i = 0; i < 8; ++i) q[t + i * 256] = f2b(v[i] * inv);
}

// ---------------- ln1: x = LN(src_f32 + attnO_bf16); writes f32 and bf16 ----------------
__global__ __launch_bounds__(256) void ln_dual(
    const float* __restrict__ a, const u16* __restrict__ bb,
    const float* __restrict__ g, const float* __restrict__ be,
    float* __restrict__ out32, u16* __restrict__ out16)
{
    const long base = (long)blockIdx.x * 1024;
    const int t = threadIdx.x;
    float v[4]; float s = 0.f, ss = 0.f;
#pragma unroll
    for (int i = 0; i < 4; ++i) {
        const int c = t + i * 256;
        const float x = a[base + c] + b2f(bb[base + c]);
        v[i] = x; s += x; ss += x * x;
    }
    __shared__ float rs[256], rss[256];
    rs[t] = s; rss[t] = ss; __syncthreads();
    for (int off = 128; off > 0; off >>= 1) {
        if (t < off) { rs[t] += rs[t + off]; rss[t] += rss[t + off]; }
        __syncthreads();
    }
    const float mean = rs[0] * (1.f / 1024.f);
    const float var = rss[0] * (1.f / 1024.f) - mean * mean;
    const float rstd = rsqrtf(var + 1e-5f);
#pragma unroll
    for (int i = 0; i < 4; ++i) {
        const int c = t + i * 256;
        const float y = (v[i] - mean) * rstd * g[c] + be[c];
        out32[base + c] = y;
        out16[base + c] = f2b(y);
    }
}

// ---------------- ln2: out_f32 = LN(x_f32 + ffO_f32) ----------------
__global__ __launch_bounds__(256) void ln_f32(
    const float* __restrict__ a, const float* __restrict__ bb,
    const float* __restrict__ g, const float* __restrict__ be,
    float* __restrict__ out)
{
    const long base = (long)blockIdx.x * 1024;
    const int t = threadIdx.x;
    float v[4]; float s = 0.f, ss = 0.f;
#pragma unroll
    for (int i = 0; i < 4; ++i) {
        const int c = t + i * 256;
        const float x = a[base + c] + bb[base + c];
        v[i] = x; s += x; ss += x * x;
    }
    __shared__ float rs[256], rss[256];
    rs[t] = s; rss[t] = ss; __syncthreads();
    for (int off = 128; off > 0; off >>= 1) {
        if (t < off) { rs[t] += rs[t + off]; rss[t] += rss[t + off]; }
        __syncthreads();
    }
    const float mean = rs[0] * (1.f / 1024.f);
    const float var = rss[0] * (1.f / 1024.f) - mean * mean;
    const float rstd = rsqrtf(var + 1e-5f);
#pragma unroll
    for (int i = 0; i < 4; ++i) {
        const int c = t + i * 256;
        out[base + c] = (v[i] - mean) * rstd * g[c] + be[c];
    }
}

extern "C" void kernel_launch(void* const* d_in, const int* in_sizes, int n_in,
                              void* d_out, int out_size, void* d_ws, size_t ws_size,
                              hipStream_t stream) {
    (void)in_sizes; (void)n_in; (void)out_size; (void)ws_size;
    constexpr long S = 2048, E = 1024, F = 4096, M = 8192;

    const float* src = (const float*)d_in[0];
    const float* Wq  = (const float*)d_in[1];
    const float* bq  = (const float*)d_in[2];
    const float* Wk  = (const float*)d_in[3];
    const float* bk  = (const float*)d_in[4];
    const float* Wv  = (const float*)d_in[5];
    const float* bv  = (const float*)d_in[6];
    const float* Wo  = (const float*)d_in[7];
    const float* bo  = (const float*)d_in[8];
    const float* W1  = (const float*)d_in[9];
    const float* b1  = (const float*)d_in[10];
    const float* W2  = (const float*)d_in[11];
    const float* b2  = (const float*)d_in[12];
    const float* g1  = (const float*)d_in[13];
    const float* be1 = (const float*)d_in[14];
    const float* g2  = (const float*)d_in[15];
    const float* be2 = (const float*)d_in[16];

    char* ws = (char*)d_ws;
    size_t off = 0;
    auto take = [&](size_t bytes) {
        char* p = ws + off;
        off += (bytes + 255) & ~(size_t)255;
        return p;
    };
    const size_t MB16 = 16777216;  // bf16 [8192][1024]
    u16* srch   = (u16*)take(MB16);
    u16* srcl   = (u16*)take(MB16);
    u16* WqkTh  = (u16*)take(2 * E * E * 2);   // [2048][1024]: WqT | WkT
    u16* WqkTl  = (u16*)take(2 * E * E * 2);
    u16* WvT    = (u16*)take(E * E * 2);
    u16* WoT    = (u16*)take(E * E * 2);
    float* qkb  = (float*)take(2 * E * 4);     // bq | bk
    char* R1    = take(4ull * S * S * 4);      // 67.1 MB
    char* R2    = take(5 * MB16);              // 80 MB

    // R1 internal (time-multiplexed)
    u16*   Vb  = (u16*)R1;                        // until VT transpose
    float* Sf  = (float*)R1;                      // scores f32; P bf16 in-place
    u16*   xb  = (u16*)R1;                        // after PV
    float* ffO = (float*)(R1 + MB16);             // [16M,48M)
    u16*   W1T = (u16*)(R1 + 3 * MB16);           // [48M,56M)
    u16*   W2T = (u16*)(R1 + 3 * MB16 + 8388608); // [56M,64M)
    // R2 internal
    u16* QKh   = (u16*)R2;                        // [0,32M): [8192][2048] hi (Q|K)
    u16* QKl   = (u16*)(R2 + 2 * MB16);           // [32M,64M)
    u16* VT    = (u16*)(R2 + 4 * MB16);           // [64M,80M)
    u16* attn  = (u16*)R2;                        // [0,16M) after scores
    u16* attnO = (u16*)(R2 + MB16);               // [16M,32M)
    float* x32 = (float*)srch;                    // 32MB over srch+srcl

    dim3 blk(256), tb(32, 8);

    split_f32<<<dim3(M * E / 4 / 256), blk, 0, stream>>>(src, srch, srcl, M * E / 4);

    transpose_f32<true ><<<dim3(32, 32), tb, 0, stream>>>(Wq, E, WqkTh,         WqkTl,         E);
    transpose_f32<true ><<<dim3(32, 32), tb, 0, stream>>>(Wk, E, WqkTh + E * E, WqkTl + E * E, E);
    transpose_f32<false><<<dim3(32, 32), tb, 0, stream>>>(Wv, E, WvT, nullptr, E);
    transpose_f32<false><<<dim3(32, 32), tb, 0, stream>>>(Wo, E, WoT, nullptr, E);
    hipMemcpyAsync(qkb,     bq, E * 4, hipMemcpyDeviceToDevice, stream);
    hipMemcpyAsync(qkb + E, bk, E * 4, hipMemcpyDeviceToDevice, stream);

    // merged Q|K projection (emulated f32): [8192][2048] hi/lo, ldc 2048
    gemm3<true><<<dim3(16, 64, 1), blk, 0, stream>>>(
        srch, srcl, srch, E, 0,
        WqkTh, WqkTh, WqkTl, E, 0,
        QKh, QKl, 2 * E, 0, qkb);

    // V projection (plain bf16) then V^T per batch
    gemm_bt<false, true, false><<<dim3(8, 64, 1), blk, 0, stream>>>(
        srch, E, 0, WvT, E, 0, Vb, E, 0, bv, E);
    transpose_bf16<<<dim3(32, 64, 4), tb, 0, stream>>>(
        Vb, E, S * E, VT, S, E * S);

    // scores (emulated f32): Sf[b] = Qh@Kh^T + Ql@Kh^T + Qh@Kl^T
    gemm3<false><<<dim3(16, 16, 4), blk, 0, stream>>>(
        QKh, QKl, QKh, 2 * E, S * 2 * E,
        QKh + E, QKh + E, QKl + E, 2 * E, S * 2 * E,
        Sf, nullptr, S, S * S, nullptr);

    softmax_rows<<<dim3(M), blk, 0, stream>>>(Sf);

    // attn[b] = P[b] @ V[b]
    gemm_bt<false, false, false><<<dim3(8, 16, 4), blk, 0, stream>>>(
        (const u16*)Sf, 2 * S, S * 2 * S, VT, S, E * S, attn, E, S * E, nullptr, S);

    // attnO = attn @ Wo + bo
    gemm_bt<false, true, false><<<dim3(8, 64, 1), blk, 0, stream>>>(
        attn, E, 0, WoT, E, 0, attnO, E, 0, bo, E);

    ln_dual<<<dim3(M), blk, 0, stream>>>(src, attnO, g1, be1, x32, xb);

    transpose_f32<false><<<dim3(128, 32), tb, 0, stream>>>(W1, F, W1T, nullptr, E);
    transpose_f32<false><<<dim3(32, 128), tb, 0, stream>>>(W2, E, W2T, nullptr, F);

    u16* h = (u16*)R2;
    gemm_bt<false, true, true><<<dim3(32, 64, 1), blk, 0, stream>>>(
        xb, E, 0, W1T, E, 0, h, F, 0, b1, E);

    gemm_bt<true, true, false><<<dim3(8, 64, 1), blk, 0, stream>>>(
        h, F, 0, W2T, F, 0, ffO, E, 0, b2, F);

    ln_f32<<<dim3(M), blk, 0, stream>>>(x32, ffO, g2, be2, (float*)d_out);
}

// Round 6
// 609.292 us; speedup vs baseline: 1.4387x; 1.2018x over previous
//
#include <hip/hip_runtime.h>
#include <stdint.h>

typedef unsigned short u16;
typedef _Float16 v8h __attribute__((ext_vector_type(8)));
typedef float v4f __attribute__((ext_vector_type(4)));

static __device__ __forceinline__ float h2f(u16 u) {
    union { u16 s; _Float16 h; } v; v.s = u; return (float)v.h;
}
static __device__ __forceinline__ u16 f2h(float f) {
    union { u16 s; _Float16 h; } v; v.h = (_Float16)f; return v.s;
}

// async global->LDS, 16B per lane. lds dest = wave-uniform base + lane*16.
static __device__ __forceinline__ void gload_lds16(const u16* g, const u16* l) {
    __builtin_amdgcn_global_load_lds(
        (const __attribute__((address_space(1))) uint32_t*)(uintptr_t)g,
        (__attribute__((address_space(3))) uint32_t*)(uintptr_t)l,
        16, 0, 0);
}

// ---------------- convert f32 -> f16, vectorized x8 ----------------
__global__ __launch_bounds__(256) void cvt_f16(const float* __restrict__ in,
                                               u16* __restrict__ out, int n8) {
    const int i = blockIdx.x * 256 + threadIdx.x;
    if (i >= n8) return;
    const float4 a = ((const float4*)in)[2 * i];
    const float4 b = ((const float4*)in)[2 * i + 1];
    u16 o[8] = {f2h(a.x), f2h(a.y), f2h(a.z), f2h(a.w),
                f2h(b.x), f2h(b.y), f2h(b.z), f2h(b.w)};
    *(uint4*)(out + (size_t)i * 8) = *(const uint4*)o;
}

// ---------------- transpose f32 [R][C] -> f16 [C][R] ----------------
__global__ __launch_bounds__(256) void transpose_f2h(
    const float* __restrict__ in, long ld_in,
    u16* __restrict__ out, long ld_out)
{
    __shared__ float tile[32][33];
    const int r0 = blockIdx.y * 32, c0 = blockIdx.x * 32;
    for (int i = threadIdx.y; i < 32; i += 8)
        tile[i][threadIdx.x] = in[(long)(r0 + i) * ld_in + c0 + threadIdx.x];
    __syncthreads();
    for (int i = threadIdx.y; i < 32; i += 8)
        out[(long)(c0 + i) * ld_out + r0 + threadIdx.x] = f2h(tile[threadIdx.x][i]);
}

// ======== f16 GEMM: C = A @ B^T (+bias)(+relu) ========
// OMODE: 0 = f16 out, 1 = f32 out, 2 = f16 transposed-batched out (C[b][col][row], b from m0)
// BK=64, XOR-swizzled LDS (conflict-free), 32 MFMA per barrier-pair.
template<int OMODE, bool BIAS, bool RELU>
__global__ __launch_bounds__(256) void gemm_f16(
    const u16* __restrict__ A, long lda, long Asb,
    const u16* __restrict__ B, long ldb, long Bsb,
    void* __restrict__ Cv, long ldc, long Csb,
    const float* __restrict__ bias, int K)
{
    alignas(16) __shared__ u16 As[128 * 64];
    alignas(16) __shared__ u16 Bs[128 * 64];
    const int t = threadIdx.x;
    const long b = blockIdx.z;
    A += b * Asb; B += b * Bsb;
    const long m0 = (long)blockIdx.y * 128;
    const long n0 = (long)blockIdx.x * 128;
    const int lane = t & 63, wave = t >> 6;
    const int wm = (wave >> 1) * 64, wn = (wave & 1) * 64;
    const int l16 = lane & 15, quad = lane >> 4;

    const int rr = t >> 3;                           // 0..31
    const int cg8 = ((t & 7) ^ ((t >> 3) & 7)) * 8;  // lane-permuted col (elts)
    const int wv512 = wave * 512;

    v4f acc[4][4];
#pragma unroll
    for (int i = 0; i < 4; ++i)
#pragma unroll
        for (int j = 0; j < 4; ++j)
            acc[i][j] = (v4f){0.f, 0.f, 0.f, 0.f};

    for (int k0 = 0; k0 < K; k0 += 64) {
        __syncthreads();
#pragma unroll
        for (int p = 0; p < 4; ++p) {
            gload_lds16(&A[(m0 + p * 32 + rr) * lda + k0 + cg8], As + p * 2048 + wv512);
            gload_lds16(&B[(n0 + p * 32 + rr) * ldb + k0 + cg8], Bs + p * 2048 + wv512);
        }
        __syncthreads();

#pragma unroll
        for (int kk = 0; kk < 2; ++kk) {
            const int swz = ((kk * 4 + quad) ^ (l16 & 7)) * 8;
            v8h af[4], bfr[4];
#pragma unroll
            for (int i = 0; i < 4; ++i)
                af[i] = *(const v8h*)&As[(wm + i * 16 + l16) * 64 + swz];
#pragma unroll
            for (int j = 0; j < 4; ++j)
                bfr[j] = *(const v8h*)&Bs[(wn + j * 16 + l16) * 64 + swz];
#pragma unroll
            for (int i = 0; i < 4; ++i)
#pragma unroll
                for (int j = 0; j < 4; ++j)
                    acc[i][j] = __builtin_amdgcn_mfma_f32_16x16x32_f16(af[i], bfr[j], acc[i][j], 0, 0, 0);
        }
    }

    if (OMODE == 2) {
        // transposed write: C[b][col][row], batch derived from m0 (batch rows = 2048)
        const long bb = m0 >> 11, mb = m0 & 2047;
        u16* C = (u16*)Cv + bb * Csb;
#pragma unroll
        for (int j = 0; j < 4; ++j) {
            const long col = n0 + wn + j * 16 + l16;
            const float bv = BIAS ? bias[col] : 0.f;
#pragma unroll
            for (int i = 0; i < 4; ++i) {
                const long row = mb + wm + i * 16 + quad * 4;
                u16 o[4];
#pragma unroll
                for (int r = 0; r < 4; ++r) {
                    float val = acc[i][j][r] + bv;
                    if (RELU) val = fmaxf(val, 0.f);
                    o[r] = f2h(val);
                }
                *(uint2*)&C[col * ldc + row] = *(const uint2*)o;
            }
        }
    } else {
        const long cbase = b * Csb;
#pragma unroll
        for (int j = 0; j < 4; ++j) {
            const long col = n0 + wn + j * 16 + l16;
            float bv = 0.f;
            if (BIAS) bv = bias[col];
#pragma unroll
            for (int i = 0; i < 4; ++i) {
                const long row = m0 + wm + i * 16 + quad * 4;
#pragma unroll
                for (int r = 0; r < 4; ++r) {
                    float val = acc[i][j][r];
                    if (BIAS) val += bv;
                    if (RELU) val = fmaxf(val, 0.f);
                    const long idx = cbase + (row + r) * ldc + col;
                    if (OMODE == 1) ((float*)Cv)[idx] = val;
                    else            ((u16*)Cv)[idx] = f2h(val);
                }
            }
        }
    }
}

// ---------------- softmax over f32 rows of 2048 -> f16 P in-place at row start ----------------
__global__ __launch_bounds__(256) void softmax_rows(float* __restrict__ S) {
    const long row = blockIdx.x;
    float* p = S + row * 2048;
    const int t = threadIdx.x;
    float v[8];
    float mx = -1e30f;
#pragma unroll
    for (int i = 0; i < 8; ++i) { v[i] = p[t + i * 256]; mx = fmaxf(mx, v[i]); }
    __shared__ float red[256];
    red[t] = mx; __syncthreads();
    for (int off = 128; off > 0; off >>= 1) {
        if (t < off) red[t] = fmaxf(red[t], red[t + off]);
        __syncthreads();
    }
    mx = red[0]; __syncthreads();
    float sum = 0.f;
#pragma unroll
    for (int i = 0; i < 8; ++i) { v[i] = __expf(v[i] - mx); sum += v[i]; }
    red[t] = sum; __syncthreads();
    for (int off = 128; off > 0; off >>= 1) {
        if (t < off) red[t] += red[t + off];
        __syncthreads();
    }
    const float inv = 1.f / red[0];
    u16* q = (u16*)p;
#pragma unroll
    for (int i = 0; i < 8; ++i) q[t + i * 256] = f2h(v[i] * inv);
}

// ---------------- ln1: x = LN(src_f32 + attnO_f16); writes f32 and f16 ----------------
__global__ __launch_bounds__(256) void ln_dual(
    const float* __restrict__ a, const u16* __restrict__ bb,
    const float* __restrict__ g, const float* __restrict__ be,
    float* __restrict__ out32, u16* __restrict__ out16)
{
    const long base = (long)blockIdx.x * 1024;
    const int t = threadIdx.x;
    float v[4]; float s = 0.f, ss = 0.f;
#pragma unroll
    for (int i = 0; i < 4; ++i) {
        const int c = t + i * 256;
        const float x = a[base + c] + h2f(bb[base + c]);
        v[i] = x; s += x; ss += x * x;
    }
    __shared__ float rs[256], rss[256];
    rs[t] = s; rss[t] = ss; __syncthreads();
    for (int off = 128; off > 0; off >>= 1) {
        if (t < off) { rs[t] += rs[t + off]; rss[t] += rss[t + off]; }
        __syncthreads();
    }
    const float mean = rs[0] * (1.f / 1024.f);
    const float var = rss[0] * (1.f / 1024.f) - mean * mean;
    const float rstd = rsqrtf(var + 1e-5f);
#pragma unroll
    for (int i = 0; i < 4; ++i) {
        const int c = t + i * 256;
        const float y = (v[i] - mean) * rstd * g[c] + be[c];
        out32[base + c] = y;
        out16[base + c] = f2h(y);
    }
}

// ---------------- ln2: out_f32 = LN(x_f32 + ffO_f32) ----------------
__global__ __launch_bounds__(256) void ln_f32(
    const float* __restrict__ a, const float* __restrict__ bb,
    const float* __restrict__ g, const float* __restrict__ be,
    float* __restrict__ out)
{
    const long base = (long)blockIdx.x * 1024;
    const int t = threadIdx.x;
    float v[4]; float s = 0.f, ss = 0.f;
#pragma unroll
    for (int i = 0; i < 4; ++i) {
        const int c = t + i * 256;
        const float x = a[base + c] + bb[base + c];
        v[i] = x; s += x; ss += x * x;
    }
    __shared__ float rs[256], rss[256];
    rs[t] = s; rss[t] = ss; __syncthreads();
    for (int off = 128; off > 0; off >>= 1) {
        if (t < off) { rs[t] += rs[t + off]; rss[t] += rss[t + off]; }
        __syncthreads();
    }
    const float mean = rs[0] * (1.f / 1024.f);
    const float var = rss[0] * (1.f / 1024.f) - mean * mean;
    const float rstd = rsqrtf(var + 1e-5f);
#pragma unroll
    for (int i = 0; i < 4; ++i) {
        const int c = t + i * 256;
        out[base + c] = (v[i] - mean) * rstd * g[c] + be[c];
    }
}

extern "C" void kernel_launch(void* const* d_in, const int* in_sizes, int n_in,
                              void* d_out, int out_size, void* d_ws, size_t ws_size,
                              hipStream_t stream) {
    (void)in_sizes; (void)n_in; (void)out_size; (void)ws_size;
    constexpr long S = 2048, E = 1024, F = 4096, M = 8192;

    const float* src = (const float*)d_in[0];
    const float* Wq  = (const float*)d_in[1];
    const float* bq  = (const float*)d_in[2];
    const float* Wk  = (const float*)d_in[3];
    const float* bk  = (const float*)d_in[4];
    const float* Wv  = (const float*)d_in[5];
    const float* bv  = (const float*)d_in[6];
    const float* Wo  = (const float*)d_in[7];
    const float* bo  = (const float*)d_in[8];
    const float* W1  = (const float*)d_in[9];
    const float* b1  = (const float*)d_in[10];
    const float* W2  = (const float*)d_in[11];
    const float* b2  = (const float*)d_in[12];
    const float* g1  = (const float*)d_in[13];
    const float* be1 = (const float*)d_in[14];
    const float* g2  = (const float*)d_in[15];
    const float* be2 = (const float*)d_in[16];

    char* ws = (char*)d_ws;
    size_t off = 0;
    auto take = [&](size_t bytes) {
        char* p = ws + off;
        off += (bytes + 255) & ~(size_t)255;
        return p;
    };
    const size_t MB16 = 16777216;  // f16 [8192][1024]
    u16*   srcH  = (u16*)take(MB16);              // dead after V proj
    u16*   WqkT  = (u16*)take(2 * E * E * 2);     // [2048][1024]: WqT | WkT
    u16*   WvT   = (u16*)take(E * E * 2);
    u16*   WoT   = (u16*)take(E * E * 2);
    u16*   W1T   = (u16*)take(F * E * 2);         // [4096][1024]
    u16*   W2T   = (u16*)take(E * F * 2);         // [1024][4096]
    float* qkb   = (float*)take(2 * E * 4);       // bq | bk
    char*  B0    = take(2 * MB16);                // QK f16 [8192][2048] -> x32 f32
    char*  B1    = take(MB16);                    // VT f16 [4][1024][2048]
    char*  B2    = take(4ull * S * S * 4);        // Sf f32 (P f16 in-place) -> hf f16 [8192][4096]
    char*  B3    = take(MB16);                    // attn f16 -> xh f16 -> ffO[0:16M)
    char*  B4    = take(MB16);                    // attnO f16 -> ffO[16M:32M)

    u16*   QK    = (u16*)B0;
    float* x32   = (float*)B0;
    u16*   VT    = (u16*)B1;
    float* Sf    = (float*)B2;
    u16*   hf    = (u16*)B2;
    u16*   attn  = (u16*)B3;
    u16*   xh    = (u16*)B3;
    u16*   attnO = (u16*)B4;
    float* ffO   = (float*)B3;                    // 32MB spanning B3+B4 (contiguous)

    dim3 blk(256), tb(32, 8);

    // 1) convert src -> f16
    cvt_f16<<<dim3(M * E / 8 / 256), blk, 0, stream>>>(src, srcH, M * E / 8);

    // 2) weight transposes f32 -> f16
    transpose_f2h<<<dim3(32, 32), tb, 0, stream>>>(Wq, E, WqkT,         E);
    transpose_f2h<<<dim3(32, 32), tb, 0, stream>>>(Wk, E, WqkT + E * E, E);
    transpose_f2h<<<dim3(32, 32), tb, 0, stream>>>(Wv, E, WvT, E);
    transpose_f2h<<<dim3(32, 32), tb, 0, stream>>>(Wo, E, WoT, E);
    transpose_f2h<<<dim3(128, 32), tb, 0, stream>>>(W1, F, W1T, E);   // [1024][4096] -> [4096][1024]
    transpose_f2h<<<dim3(32, 128), tb, 0, stream>>>(W2, E, W2T, F);   // [4096][1024] -> [1024][4096]
    hipMemcpyAsync(qkb,     bq, E * 4, hipMemcpyDeviceToDevice, stream);
    hipMemcpyAsync(qkb + E, bk, E * 4, hipMemcpyDeviceToDevice, stream);

    // 3) merged Q|K projection: QK [8192][2048] f16
    gemm_f16<0, true, false><<<dim3(16, 64, 1), blk, 0, stream>>>(
        srcH, E, 0, WqkT, E, 0, QK, 2 * E, 0, qkb, E);

    // 4) V projection with transposed write: VT[b][col][row]
    gemm_f16<2, true, false><<<dim3(8, 64, 1), blk, 0, stream>>>(
        srcH, E, 0, WvT, E, 0, VT, S, E * S, bv, E);

    // 5) scores[b] = Q[b] @ K[b]^T (f32 out)
    gemm_f16<1, false, false><<<dim3(16, 16, 4), blk, 0, stream>>>(
        QK, 2 * E, S * 2 * E, QK + E, 2 * E, S * 2 * E,
        Sf, S, S * S, nullptr, E);

    // 6) softmax (f32 in, f16 P in-place, row pitch 4096 halves)
    softmax_rows<<<dim3(M), blk, 0, stream>>>(Sf);

    // 7) attn[b] = P[b] @ V[b]
    gemm_f16<0, false, false><<<dim3(8, 16, 4), blk, 0, stream>>>(
        (const u16*)Sf, 2 * S, S * 2 * S, VT, S, E * S,
        attn, E, S * E, nullptr, S);

    // 8) attnO = attn @ Wo + bo (f16)
    gemm_f16<0, true, false><<<dim3(8, 64, 1), blk, 0, stream>>>(
        attn, E, 0, WoT, E, 0, attnO, E, 0, bo, E);

    // 9) x = LN(src + attnO) -> x32 (f32, over dead QK) and xh (f16, over dead attn)
    ln_dual<<<dim3(M), blk, 0, stream>>>(src, attnO, g1, be1, x32, xh);

    // 10) hf = relu(xh @ W1 + b1) (f16, over dead Sf/P)
    gemm_f16<0, true, true><<<dim3(32, 64, 1), blk, 0, stream>>>(
        xh, E, 0, W1T, E, 0, hf, F, 0, b1, E);

    // 11) ffO = hf @ W2 + b2 (f32, over dead xh+attnO)
    gemm_f16<1, true, false><<<dim3(8, 64, 1), blk, 0, stream>>>(
        hf, F, 0, W2T, F, 0, ffO, E, 0, b2, F);

    // 12) out = LN(x32 + ffO) -> f32
    ln_f32<<<dim3(M), blk, 0, stream>>>(x32, ffO, g2, be2, (float*)d_out);
}

// Round 7
// 558.053 us; speedup vs baseline: 1.5708x; 1.0918x over previous
//
#include <hip/hip_runtime.h>
#include <stdint.h>

typedef unsigned short u16;
typedef _Float16 v8h __attribute__((ext_vector_type(8)));
typedef float v4f __attribute__((ext_vector_type(4)));

static __device__ __forceinline__ float h2f(u16 u) {
    union { u16 s; _Float16 h; } v; v.s = u; return (float)v.h;
}
static __device__ __forceinline__ u16 f2h(float f) {
    union { u16 s; _Float16 h; } v; v.h = (_Float16)f; return v.s;
}

// async global->LDS, 16B per lane. lds dest = wave-uniform base + lane*16.
static __device__ __forceinline__ void gload_lds16(const u16* g, const u16* l) {
    __builtin_amdgcn_global_load_lds(
        (const __attribute__((address_space(1))) uint32_t*)(uintptr_t)g,
        (__attribute__((address_space(3))) uint32_t*)(uintptr_t)l,
        16, 0, 0);
}

// ---------------- convert f32 -> f16, vectorized x8 ----------------
__global__ __launch_bounds__(256) void cvt_f16(const float* __restrict__ in,
                                               u16* __restrict__ out, int n8) {
    const int i = blockIdx.x * 256 + threadIdx.x;
    if (i >= n8) return;
    const float4 a = ((const float4*)in)[2 * i];
    const float4 b = ((const float4*)in)[2 * i + 1];
    u16 o[8] = {f2h(a.x), f2h(a.y), f2h(a.z), f2h(a.w),
                f2h(b.x), f2h(b.y), f2h(b.z), f2h(b.w)};
    *(uint4*)(out + (size_t)i * 8) = *(const uint4*)o;
}

// ---------------- all weight transposes f32 [R][C] -> f16 [C][R], one launch ----------------
__global__ __launch_bounds__(256) void transpose_all(
    const float* __restrict__ Wq, const float* __restrict__ Wk,
    const float* __restrict__ Wv, const float* __restrict__ Wo,
    const float* __restrict__ W1, const float* __restrict__ W2,
    u16* __restrict__ WqkT, u16* __restrict__ WvT, u16* __restrict__ WoT,
    u16* __restrict__ W1T, u16* __restrict__ W2T)
{
    int t = blockIdx.x;
    const float* in; u16* out; long ldi, ldo; int xt;
    if (t < 1024)      {            in = Wq; out = WqkT;              ldi = 1024; ldo = 1024; xt = 32; }
    else if (t < 2048) { t -= 1024; in = Wk; out = WqkT + 1024*1024;  ldi = 1024; ldo = 1024; xt = 32; }
    else if (t < 3072) { t -= 2048; in = Wv; out = WvT;               ldi = 1024; ldo = 1024; xt = 32; }
    else if (t < 4096) { t -= 3072; in = Wo; out = WoT;               ldi = 1024; ldo = 1024; xt = 32; }
    else if (t < 8192) { t -= 4096; in = W1; out = W1T;               ldi = 4096; ldo = 1024; xt = 128; }
    else               { t -= 8192; in = W2; out = W2T;               ldi = 1024; ldo = 4096; xt = 32; }
    const int c0 = (t % xt) * 32, r0 = (t / xt) * 32;
    __shared__ float tile[32][33];
    for (int i = threadIdx.y; i < 32; i += 8)
        tile[i][threadIdx.x] = in[(long)(r0 + i) * ldi + c0 + threadIdx.x];
    __syncthreads();
    for (int i = threadIdx.y; i < 32; i += 8)
        out[(long)(c0 + i) * ldo + r0 + threadIdx.x] = f2h(tile[threadIdx.x][i]);
}

// ======== f16 GEMM: C = A @ B^T (+bias)(+relu) ========
// OMODE: 0 = f16 out, 1 = f32 out, 2 = f16 transposed-batched out (C[b][col][row], b from m0)
// BIAS: 0 none, 1 single, 2 dual (bias for col<1024, bias2 for col>=1024)
// BK=64, XOR-swizzled LDS (conflict-free), 32 MFMA per barrier-pair.
template<int OMODE, int BIAS, bool RELU>
__global__ __launch_bounds__(256) void gemm_f16(
    const u16* __restrict__ A, long lda, long Asb,
    const u16* __restrict__ B, long ldb, long Bsb,
    void* __restrict__ Cv, long ldc, long Csb,
    const float* __restrict__ bias, const float* __restrict__ bias2, int K)
{
    alignas(16) __shared__ u16 As[128 * 64];
    alignas(16) __shared__ u16 Bs[128 * 64];
    const int t = threadIdx.x;
    const long b = blockIdx.z;
    A += b * Asb; B += b * Bsb;
    const long m0 = (long)blockIdx.y * 128;
    const long n0 = (long)blockIdx.x * 128;
    const int lane = t & 63, wave = t >> 6;
    const int wm = (wave >> 1) * 64, wn = (wave & 1) * 64;
    const int l16 = lane & 15, quad = lane >> 4;

    const int rr = t >> 3;                           // 0..31
    const int cg8 = ((t & 7) ^ ((t >> 3) & 7)) * 8;  // lane-permuted col (elts)
    const int wv512 = wave * 512;

    // hoisted per-thread global element offsets (k0 stays uniform/scalar)
    long aofs[4], bofs[4];
#pragma unroll
    for (int p = 0; p < 4; ++p) {
        aofs[p] = (m0 + p * 32 + rr) * lda + cg8;
        bofs[p] = (n0 + p * 32 + rr) * ldb + cg8;
    }

    v4f acc[4][4];
#pragma unroll
    for (int i = 0; i < 4; ++i)
#pragma unroll
        for (int j = 0; j < 4; ++j)
            acc[i][j] = (v4f){0.f, 0.f, 0.f, 0.f};

    for (int k0 = 0; k0 < K; k0 += 64) {
        __syncthreads();
#pragma unroll
        for (int p = 0; p < 4; ++p) {
            gload_lds16(A + aofs[p] + k0, As + p * 2048 + wv512);
            gload_lds16(B + bofs[p] + k0, Bs + p * 2048 + wv512);
        }
        __syncthreads();

#pragma unroll
        for (int kk = 0; kk < 2; ++kk) {
            const int swz = ((kk * 4 + quad) ^ (l16 & 7)) * 8;
            v8h af[4], bfr[4];
#pragma unroll
            for (int i = 0; i < 4; ++i)
                af[i] = *(const v8h*)&As[(wm + i * 16 + l16) * 64 + swz];
#pragma unroll
            for (int j = 0; j < 4; ++j)
                bfr[j] = *(const v8h*)&Bs[(wn + j * 16 + l16) * 64 + swz];
#pragma unroll
            for (int i = 0; i < 4; ++i)
#pragma unroll
                for (int j = 0; j < 4; ++j)
                    acc[i][j] = __builtin_amdgcn_mfma_f32_16x16x32_f16(af[i], bfr[j], acc[i][j], 0, 0, 0);
        }
    }

    // per-j bias
    float bv[4];
#pragma unroll
    for (int j = 0; j < 4; ++j) {
        const long col = n0 + wn + j * 16 + l16;
        bv[j] = (BIAS == 0) ? 0.f
              : (BIAS == 1) ? bias[col]
              : (col < 1024 ? bias[col] : bias2[col - 1024]);
    }

    if (OMODE == 2) {
        // transposed write: C[b][col][row], batch derived from m0 (batch rows = 2048)
        const long bb = m0 >> 11, mb = m0 & 2047;
        u16* C = (u16*)Cv + bb * Csb;
#pragma unroll
        for (int j = 0; j < 4; ++j) {
            const long col = n0 + wn + j * 16 + l16;
            u16* pc = C + col * ldc + mb + wm + quad * 4;
#pragma unroll
            for (int i = 0; i < 4; ++i) {
                u16 o[4];
#pragma unroll
                for (int r = 0; r < 4; ++r) {
                    float val = acc[i][j][r] + bv[j];
                    if (RELU) val = fmaxf(val, 0.f);
                    o[r] = f2h(val);
                }
                *(uint2*)(pc + i * 16) = *(const uint2*)o;
            }
        }
    } else {
        const long cb = b * Csb + (m0 + wm + quad * 4) * ldc + (n0 + wn + l16);
        if (OMODE == 1) {
            float* p0 = (float*)Cv + cb;
#pragma unroll
            for (int i = 0; i < 4; ++i)
#pragma unroll
                for (int r = 0; r < 4; ++r) {
                    float* prow = p0 + (long)(i * 16 + r) * ldc;
#pragma unroll
                    for (int j = 0; j < 4; ++j) {
                        float val = acc[i][j][r] + bv[j];
                        if (RELU) val = fmaxf(val, 0.f);
                        prow[j * 16] = val;
                    }
                }
        } else {
            u16* p0 = (u16*)Cv + cb;
#pragma unroll
            for (int i = 0; i < 4; ++i)
#pragma unroll
                for (int r = 0; r < 4; ++r) {
                    u16* prow = p0 + (long)(i * 16 + r) * ldc;
#pragma unroll
                    for (int j = 0; j < 4; ++j) {
                        float val = acc[i][j][r] + bv[j];
                        if (RELU) val = fmaxf(val, 0.f);
                        prow[j * 16] = f2h(val);
                    }
                }
        }
    }
}

// ---------------- softmax over f32 rows of 2048 -> f16 P in-place at row start ----------------
__global__ __launch_bounds__(256) void softmax_rows(float* __restrict__ S) {
    const long row = blockIdx.x;
    float* p = S + row * 2048;
    const int t = threadIdx.x;
    float v[8];
    float mx = -1e30f;
#pragma unroll
    for (int i = 0; i < 8; ++i) { v[i] = p[t + i * 256]; mx = fmaxf(mx, v[i]); }
    __shared__ float red[256];
    red[t] = mx; __syncthreads();
    for (int off = 128; off > 0; off >>= 1) {
        if (t < off) red[t] = fmaxf(red[t], red[t + off]);
        __syncthreads();
    }
    mx = red[0]; __syncthreads();
    float sum = 0.f;
#pragma unroll
    for (int i = 0; i < 8; ++i) { v[i] = __expf(v[i] - mx); sum += v[i]; }
    red[t] = sum; __syncthreads();
    for (int off = 128; off > 0; off >>= 1) {
        if (t < off) red[t] += red[t + off];
        __syncthreads();
    }
    const float inv = 1.f / red[0];
    u16* q = (u16*)p;
#pragma unroll
    for (int i = 0; i < 8; ++i) q[t + i * 256] = f2h(v[i] * inv);
}

// ---------------- ln1: x = LN(src_f32 + attnO_f16); writes f32 and f16 ----------------
__global__ __launch_bounds__(256) void ln_dual(
    const float* __restrict__ a, const u16* __restrict__ bb,
    const float* __restrict__ g, const float* __restrict__ be,
    float* __restrict__ out32, u16* __restrict__ out16)
{
    const long base = (long)blockIdx.x * 1024;
    const int t = threadIdx.x;
    float v[4]; float s = 0.f, ss = 0.f;
#pragma unroll
    for (int i = 0; i < 4; ++i) {
        const int c = t + i * 256;
        const float x = a[base + c] + h2f(bb[base + c]);
        v[i] = x; s += x; ss += x * x;
    }
    __shared__ float rs[256], rss[256];
    rs[t] = s; rss[t] = ss; __syncthreads();
    for (int off = 128; off > 0; off >>= 1) {
        if (t < off) { rs[t] += rs[t + off]; rss[t] += rss[t + off]; }
        __syncthreads();
    }
    const float mean = rs[0] * (1.f / 1024.f);
    const float var = rss[0] * (1.f / 1024.f) - mean * mean;
    const float rstd = rsqrtf(var + 1e-5f);
#pragma unroll
    for (int i = 0; i < 4; ++i) {
        const int c = t + i * 256;
        const float y = (v[i] - mean) * rstd * g[c] + be[c];
        out32[base + c] = y;
        out16[base + c] = f2h(y);
    }
}

// ---------------- ln2: out_f32 = LN(x_f32 + ffO_f16) ----------------
__global__ __launch_bounds__(256) void ln_mix(
    const float* __restrict__ a, const u16* __restrict__ bb,
    const float* __restrict__ g, const float* __restrict__ be,
    float* __restrict__ out)
{
    const long base = (long)blockIdx.x * 1024;
    const int t = threadIdx.x;
    float v[4]; float s = 0.f, ss = 0.f;
#pragma unroll
    for (int i = 0; i < 4; ++i) {
        const int c = t + i * 256;
        const float x = a[base + c] + h2f(bb[base + c]);
        v[i] = x; s += x; ss += x * x;
    }
    __shared__ float rs[256], rss[256];
    rs[t] = s; rss[t] = ss; __syncthreads();
    for (int off = 128; off > 0; off >>= 1) {
        if (t < off) { rs[t] += rs[t + off]; rss[t] += rss[t + off]; }
        __syncthreads();
    }
    const float mean = rs[0] * (1.f / 1024.f);
    const float var = rss[0] * (1.f / 1024.f) - mean * mean;
    const float rstd = rsqrtf(var + 1e-5f);
#pragma unroll
    for (int i = 0; i < 4; ++i) {
        const int c = t + i * 256;
        out[base + c] = (v[i] - mean) * rstd * g[c] + be[c];
    }
}

extern "C" void kernel_launch(void* const* d_in, const int* in_sizes, int n_in,
                              void* d_out, int out_size, void* d_ws, size_t ws_size,
                              hipStream_t stream) {
    (void)in_sizes; (void)n_in; (void)out_size; (void)ws_size;
    constexpr long S = 2048, E = 1024, F = 4096, M = 8192;

    const float* src = (const float*)d_in[0];
    const float* Wq  = (const float*)d_in[1];
    const float* bq  = (const float*)d_in[2];
    const float* Wk  = (const float*)d_in[3];
    const float* bk  = (const float*)d_in[4];
    const float* Wv  = (const float*)d_in[5];
    const float* bv  = (const float*)d_in[6];
    const float* Wo  = (const float*)d_in[7];
    const float* bo  = (const float*)d_in[8];
    const float* W1  = (const float*)d_in[9];
    const float* b1  = (const float*)d_in[10];
    const float* W2  = (const float*)d_in[11];
    const float* b2  = (const float*)d_in[12];
    const float* g1  = (const float*)d_in[13];
    const float* be1 = (const float*)d_in[14];
    const float* g2  = (const float*)d_in[15];
    const float* be2 = (const float*)d_in[16];

    char* ws = (char*)d_ws;
    size_t off = 0;
    auto take = [&](size_t bytes) {
        char* p = ws + off;
        off += (bytes + 255) & ~(size_t)255;
        return p;
    };
    const size_t MB16 = 16777216;  // f16 [8192][1024]
    u16*   srcH  = (u16*)take(MB16);
    u16*   WqkT  = (u16*)take(2 * E * E * 2);     // [2048][1024]: WqT | WkT
    u16*   WvT   = (u16*)take(E * E * 2);
    u16*   WoT   = (u16*)take(E * E * 2);
    u16*   W1T   = (u16*)take(F * E * 2);         // [4096][1024]
    u16*   W2T   = (u16*)take(E * F * 2);         // [1024][4096]
    char*  B0    = take(2 * MB16);                // QK f16 [8192][2048] -> x32 f32
    char*  B1    = take(MB16);                    // VT f16 [4][1024][2048]
    char*  B2    = take(4ull * S * S * 4);        // Sf f32 (P f16 in-place) -> hf f16 [8192][4096]
    char*  B3    = take(MB16);                    // attn f16 -> xh f16
    char*  B4    = take(MB16);                    // attnO f16 -> ffO f16

    u16*   QK    = (u16*)B0;
    float* x32   = (float*)B0;
    u16*   VT    = (u16*)B1;
    float* Sf    = (float*)B2;
    u16*   hf    = (u16*)B2;
    u16*   attn  = (u16*)B3;
    u16*   xh    = (u16*)B3;
    u16*   attnO = (u16*)B4;
    u16*   ffO   = (u16*)B4;

    dim3 blk(256), tb(32, 8);

    // 1) convert src -> f16
    cvt_f16<<<dim3(M * E / 8 / 256), blk, 0, stream>>>(src, srcH, M * E / 8);

    // 2) all weight transposes in one launch
    transpose_all<<<dim3(12288), tb, 0, stream>>>(Wq, Wk, Wv, Wo, W1, W2,
                                                  WqkT, WvT, WoT, W1T, W2T);

    // 3) merged Q|K projection: QK [8192][2048] f16 (dual bias)
    gemm_f16<0, 2, false><<<dim3(16, 64, 1), blk, 0, stream>>>(
        srcH, E, 0, WqkT, E, 0, QK, 2 * E, 0, bq, bk, E);

    // 4) V projection with transposed write: VT[b][col][row]
    gemm_f16<2, 1, false><<<dim3(8, 64, 1), blk, 0, stream>>>(
        srcH, E, 0, WvT, E, 0, VT, S, E * S, bv, nullptr, E);

    // 5) scores[b] = Q[b] @ K[b]^T (f32 out)
    gemm_f16<1, 0, false><<<dim3(16, 16, 4), blk, 0, stream>>>(
        QK, 2 * E, S * 2 * E, QK + E, 2 * E, S * 2 * E,
        Sf, S, S * S, nullptr, nullptr, E);

    // 6) softmax (f32 in, f16 P in-place, row pitch 4096 halves)
    softmax_rows<<<dim3(M), blk, 0, stream>>>(Sf);

    // 7) attn[b] = P[b] @ V[b]
    gemm_f16<0, 0, false><<<dim3(8, 16, 4), blk, 0, stream>>>(
        (const u16*)Sf, 2 * S, S * 2 * S, VT, S, E * S,
        attn, E, S * E, nullptr, nullptr, S);

    // 8) attnO = attn @ Wo + bo (f16)
    gemm_f16<0, 1, false><<<dim3(8, 64, 1), blk, 0, stream>>>(
        attn, E, 0, WoT, E, 0, attnO, E, 0, bo, nullptr, E);

    // 9) x = LN(src + attnO) -> x32 (f32, over dead QK) and xh (f16, over dead attn)
    ln_dual<<<dim3(M), blk, 0, stream>>>(src, attnO, g1, be1, x32, xh);

    // 10) hf = relu(xh @ W1 + b1) (f16, over dead Sf/P)
    gemm_f16<0, 1, true><<<dim3(32, 64, 1), blk, 0, stream>>>(
        xh, E, 0, W1T, E, 0, hf, F, 0, b1, nullptr, E);

    // 11) ffO = hf @ W2 + b2 (f16, over dead attnO)
    gemm_f16<0, 1, false><<<dim3(8, 64, 1), blk, 0, stream>>>(
        hf, F, 0, W2T, F, 0, ffO, E, 0, b2, nullptr, F);

    // 12) out = LN(x32 + ffO) -> f32
    ln_mix<<<dim3(M), blk, 0, stream>>>(x32, ffO, g2, be2, (float*)d_out);
}